// Round 1
// baseline (2700.769 us; speedup 1.0000x reference)
//
#include <hip/hip_runtime.h>
#include <math.h>

// TopologyLoss (clDice) — fully fused soft-skeletonize on MI355X.
// Tile: 64x64 interior, halo 12 (needs 11; 12 keeps 16B alignment of interior),
// LDS buffers 88x88 fp32 x2 = 62KB -> 2 blocks/CU.
// Valid region at iteration k: local [1+k, 86-k]^2. Interior: [12,75]^2.

#define STR 88
#define BIG 3.0e38f

__device__ __forceinline__ float sigmoidf_(float x) {
  return 1.0f / (1.0f + __expf(-x));
}

__global__ __launch_bounds__(256, 2) void skel_tile_kernel(
    const float* __restrict__ pred, const float* __restrict__ gt,
    float* __restrict__ sums)
{
  const int tile = blockIdx.x;   // 0..255 (16x16 tiles)
  const int b    = blockIdx.y;   // 0..31  batch
  const int s    = blockIdx.z;   // 0: skeletonize sigmoid(pred), 1: skeletonize gt
  const int txI = tile & 15, tyI = tile >> 4;
  const int x0 = txI * 64 - 12, y0 = tyI * 64 - 12;  // global coord of local 0
  const int t  = threadIdx.x;
  const int tx = t & 15, ty = t >> 4;
  const size_t base = (size_t)b * (1024u * 1024u);
  const float* __restrict__ src  = s ? gt   : pred;  // skeleton input
  const float* __restrict__ osrc = s ? pred : gt;    // product partner

  __shared__ __align__(16) float A[88 * STR];
  __shared__ __align__(16) float B[88 * STR];

  // ---- load halo tile: local [1..86]^2; out-of-image = +BIG (erode pad) ----
  for (int i = t; i < 86 * 86; i += 256) {
    int li = (i / 86) + 1, lj = (i % 86) + 1;
    int gy = y0 + li, gx = x0 + lj;
    float v = BIG;
    if ((unsigned)gy < 1024u && (unsigned)gx < 1024u) {
      v = src[base + (size_t)gy * 1024 + gx];
      if (s == 0) v = sigmoidf_(v);
    }
    A[li * STR + lj] = v;
  }
  __syncthreads();

  // each thread owns a 4x4 interior block
  const int iy = 12 + 4 * ty, ix = 12 + 4 * tx;
  float img[4][4], skel[4][4];
  for (int y = 0; y < 4; ++y)
    for (int x = 0; x < 4; ++x) {
      img[y][x]  = A[(iy + y) * STR + ix + x];
      skel[y][x] = 0.0f;
    }

  for (int k = 0; k < 10; ++k) {
    const int lo = 1 + k, hi = 86 - k;

    // rowmin: A -> B, rows [lo,hi], cols [lo+1,hi-1]
    for (int li = lo + ty; li <= hi; li += 16) {
      const int r = li * STR;
      for (int lj = lo + 1 + tx; lj <= hi - 1; lj += 16) {
        float c = A[r + lj];
        float l = A[r + lj - 1];
        float rr = A[r + lj + 1];
        B[r + lj] = fminf(c, fminf(l, rr));
      }
    }
    __syncthreads();

    // colmin: B -> A (= erode(img) = next img), region [lo+1,hi-1]^2
    for (int li = lo + 1 + ty; li <= hi - 1; li += 16) {
      const int r = li * STR;
      for (int lj = lo + 1 + tx; lj <= hi - 1; lj += 16) {
        float c = B[r + lj];
        float u = B[r - STR + lj];
        float d = B[r + STR + lj];
        A[r + lj] = fminf(c, fminf(u, d));
      }
    }
    __syncthreads();

    // save next img (e at interior) before anything else clobbers it later
    float imgn[4][4];
    for (int y = 0; y < 4; ++y)
      for (int x = 0; x < 4; ++x)
        imgn[y][x] = A[(iy + y) * STR + ix + x];

    // rowmax (dilate pass 1): A -> B, rows [11,76], cols [12,75]
    // out-of-image columns substitute -BIG (clipped max)
    for (int li = 11 + ty; li <= 76; li += 16) {
      const int r = li * STR;
      for (int lj = 12 + tx; lj <= 75; lj += 16) {
        int gx = x0 + lj;
        float c = A[r + lj];
        float l  = (gx >= 1)    ? A[r + lj - 1] : -BIG;
        float rr = (gx <= 1022) ? A[r + lj + 1] : -BIG;
        B[r + lj] = fmaxf(c, fmaxf(l, rr));
      }
    }
    __syncthreads();

    // colmax + delta + skel at interior (per-thread 4x4, registers)
    for (int y = 0; y < 4; ++y) {
      const int li = iy + y;
      const int gy = y0 + li;
      const int r = li * STR;
      for (int x = 0; x < 4; ++x) {
        const int lj = ix + x;
        float c = B[r + lj];
        float u = (gy >= 1)    ? B[r - STR + lj] : -BIG;
        float d = (gy <= 1022) ? B[r + STR + lj] : -BIG;
        float opened = fmaxf(c, fmaxf(u, d));
        float delta = fmaxf(img[y][x] - opened, 0.0f);
        skel[y][x] = fmaxf(skel[y][x], delta);
        img[y][x] = imgn[y][x];
      }
    }
    __syncthreads();
  }

  // ---- fused reduction: s0 = sum(skel * other), s1 = sum(skel) ----
  float s0 = 0.f, s1 = 0.f;
  for (int y = 0; y < 4; ++y) {
    const int gy = tyI * 64 + 4 * ty + y;
    const float4 o4 = *reinterpret_cast<const float4*>(
        &osrc[base + (size_t)gy * 1024 + txI * 64 + 4 * tx]);
    float ov[4] = {o4.x, o4.y, o4.z, o4.w};
    for (int x = 0; x < 4; ++x) {
      float o = ov[x];
      if (s == 1) o = sigmoidf_(o);  // partner of skel_gt is p = sigmoid(pred)
      s0 += skel[y][x] * o;
      s1 += skel[y][x];
    }
  }
  // wave reduce (64 lanes), then cross-wave via LDS, one atomic pair per block
  for (int off = 32; off >= 1; off >>= 1) {
    s0 += __shfl_down(s0, off, 64);
    s1 += __shfl_down(s1, off, 64);
  }
  const int lane = t & 63, wv = t >> 6;
  if (lane == 0) { A[wv * 2] = s0; A[wv * 2 + 1] = s1; }
  __syncthreads();
  if (t == 0) {
    float t0 = A[0] + A[2] + A[4] + A[6];
    float t1 = A[1] + A[3] + A[5] + A[7];
    atomicAdd(&sums[(s * 32 + b) * 2 + 0], t0);
    atomicAdd(&sums[(s * 32 + b) * 2 + 1], t1);
  }
}

__global__ void finalize_kernel(const float* __restrict__ sums,
                                float* __restrict__ out)
{
  const int t = threadIdx.x;  // 64 threads
  float cl = 0.f;
  if (t < 32) {
    float pn = sums[t * 2 + 0],        pd = sums[t * 2 + 1];
    float sn = sums[(32 + t) * 2 + 0], sd = sums[(32 + t) * 2 + 1];
    float tprec = pn / (pd + 1e-6f);
    float tsens = sn / (sd + 1e-6f);
    cl = 2.f * tprec * tsens / (tprec + tsens + 1e-6f);
  }
  for (int off = 32; off >= 1; off >>= 1) cl += __shfl_down(cl, off, 64);
  if (t == 0) out[0] = 1.f - cl / 32.f;
}

extern "C" void kernel_launch(void* const* d_in, const int* in_sizes, int n_in,
                              void* d_out, int out_size, void* d_ws, size_t ws_size,
                              hipStream_t stream) {
  const float* pred = (const float*)d_in[0];
  const float* gt   = (const float*)d_in[1];
  float* sums = (float*)d_ws;  // 128 floats: [tensor][batch][{prod,sum}]
  hipMemsetAsync(sums, 0, 128 * sizeof(float), stream);
  dim3 grid(256, 32, 2);
  skel_tile_kernel<<<grid, dim3(256), 0, stream>>>(pred, gt, sums);
  finalize_kernel<<<1, 64, 0, stream>>>(sums, (float*)d_out);
}

// Round 2
// 802.391 us; speedup vs baseline: 3.3659x; 3.3659x over previous
//
#include <hip/hip_runtime.h>
#include <math.h>

// clDice topology loss, round 2: fp16 LDS + b128 vector sweeps.
// Tile 64x64, halo 16 -> 96x96 region, 12 chunks of 8 halfs per row.
// LDS stride 104 halfs (16B aligned; 52 dwords, != 0 mod 32 to spread banks).
// Two 19.5KB buffers -> 4 blocks/CU, 16 waves/CU.
// Fixed-region passes: contamination from tile edge spreads 1 px/pass;
// after 10 erodes correct region [10,85]^2 superset of used [15,80]^2.
// One barrier per iteration (erode P->Q, barrier, dilate Q->regs).

#define STRH 104
#define ROWS 96
#define BIGF 60000.0f

typedef _Float16 half8 __attribute__((ext_vector_type(8)));

__device__ __forceinline__ float sigmoidf_(float x) {
  return 1.0f / (1.0f + __expf(-x));
}

__device__ __forceinline__ half8 splat8(float x) {
  _Float16 h = (_Float16)x;
  half8 v = {h, h, h, h, h, h, h, h};
  return v;
}
__device__ __forceinline__ half8 vmin3(half8 a, half8 b, half8 c) {
  return __builtin_elementwise_min(a, __builtin_elementwise_min(b, c));
}
__device__ __forceinline__ half8 vmax3(half8 a, half8 b, half8 c) {
  return __builtin_elementwise_max(a, __builtin_elementwise_max(b, c));
}
__device__ __forceinline__ half8 sh_r(half8 v, _Float16 l) {  // [l, v0..v6]
  half8 r;
  r[0] = l;
  #pragma unroll
  for (int j = 1; j < 8; ++j) r[j] = v[j - 1];
  return r;
}
__device__ __forceinline__ half8 sh_l(half8 v, _Float16 rr) {  // [v1..v7, rr]
  half8 r;
  #pragma unroll
  for (int j = 0; j < 7; ++j) r[j] = v[j + 1];
  r[7] = rr;
  return r;
}

// fused 3-wide horizontal min for one row of one 8-chunk
__device__ __forceinline__ half8 rowmin8(const _Float16* __restrict__ P,
                                         int row, int ci, int c0) {
  const _Float16* p = P + row * STRH + c0;
  half8 v = *(const half8*)p;
  _Float16 l = (ci != 0)  ? p[-1] : (_Float16)BIGF;
  _Float16 r = (ci != 11) ? p[8]  : (_Float16)BIGF;
  return vmin3(sh_r(v, l), v, sh_l(v, r));
}

__global__ __launch_bounds__(256, 4) void skel_tile_kernel(
    const float* __restrict__ pred, const float* __restrict__ gt,
    float* __restrict__ sums)
{
  __shared__ __align__(16) _Float16 LA[ROWS * STRH];
  __shared__ __align__(16) _Float16 LB[ROWS * STRH];

  const int tile = blockIdx.x;   // 16x16 tiles of 64x64
  const int b    = blockIdx.y;   // batch 0..31
  const int s    = blockIdx.z;   // 0: skel(sigmoid(pred)), 1: skel(gt)
  const int txI = tile & 15, tyI = tile >> 4;
  const int x0 = txI * 64 - 16, y0 = tyI * 64 - 16;
  const int t  = threadIdx.x;
  const size_t base = (size_t)b << 20;
  const float* __restrict__ src  = s ? gt   : pred;
  const float* __restrict__ osrc = s ? pred : gt;

  // ---- load 96 rows x 12 chunks; out-of-image = +BIG (erode pad) ----
  for (int i = t; i < ROWS * 12; i += 256) {
    int ci = i % 12, row = i / 12;
    int gy = y0 + row, gx0 = x0 + ci * 8;
    half8 h;
    if ((unsigned)gy < 1024u && gx0 >= 0 && gx0 + 7 < 1024) {
      const size_t g = base + (size_t)gy * 1024 + gx0;
      const float4 f0 = *(const float4*)&src[g];
      const float4 f1 = *(const float4*)&src[g + 4];
      float ff[8] = {f0.x, f0.y, f0.z, f0.w, f1.x, f1.y, f1.z, f1.w};
      #pragma unroll
      for (int e = 0; e < 8; ++e) {
        float v = (s == 0) ? sigmoidf_(ff[e]) : ff[e];
        h[e] = (_Float16)v;
      }
    } else {
      #pragma unroll
      for (int e = 0; e < 8; ++e) {
        int gx = gx0 + e;
        float v = BIGF;
        if ((unsigned)gy < 1024u && (unsigned)gx < 1024u) {
          v = src[base + (size_t)gy * 1024 + gx];
          if (s == 0) v = sigmoidf_(v);
        }
        h[e] = (_Float16)v;
      }
    }
    *(half8*)&LA[row * STRH + ci * 8] = h;
  }
  __syncthreads();

  // ---- per-thread interior ownership (dilate/skel): 8 chunks x 32 2-row segs
  const int ci_d = 2 + (t & 7), c0d = ci_d * 8;
  const int rsd  = 16 + (t >> 3) * 2;
  const int gx0d = x0 + c0d;
  const bool lclip = (gx0d == 0), rclip = (gx0d + 7 == 1023);

  half8 img[2], skel[2];
  img[0] = *(const half8*)&LA[rsd * STRH + c0d];
  img[1] = *(const half8*)&LA[(rsd + 1) * STRH + c0d];
  skel[0] = splat8(0.0f);
  skel[1] = splat8(0.0f);

  // erode ownership: 12 chunks x 16 6-row segs = 192 threads
  const int ci_e = t % 12, c0e = ci_e * 8;
  const int rse  = (t / 12) * 6;

  _Float16* P = LA;
  _Float16* Q = LB;

  for (int k = 0; k < 10; ++k) {
    // ---- fused erode (rowmin+colmin sweep): P -> Q ----
    if (t < 192) {
      half8 rm0 = (rse == 0) ? splat8(BIGF) : rowmin8(P, rse - 1, ci_e, c0e);
      half8 rm1 = rowmin8(P, rse, ci_e, c0e);
      #pragma unroll
      for (int j = 0; j < 6; ++j) {
        int rr = rse + 1 + j;
        half8 rm2 = (rr > 95) ? splat8(BIGF) : rowmin8(P, rr, ci_e, c0e);
        *(half8*)&Q[(rse + j) * STRH + c0e] = vmin3(rm0, rm1, rm2);
        rm0 = rm1;
        rm1 = rm2;
      }
    }
    __syncthreads();

    // ---- fused dilate (rowmax+colmax) at interior -> registers ----
    half8 rmx[4], raw0, raw1;
    #pragma unroll
    for (int jj = 0; jj < 4; ++jj) {
      int row = rsd - 1 + jj;
      const _Float16* p = Q + row * STRH + c0d;
      half8 v = *(const half8*)p;
      _Float16 l = lclip ? (_Float16)(-BIGF) : p[-1];
      _Float16 r = rclip ? (_Float16)(-BIGF) : p[8];
      rmx[jj] = vmax3(sh_r(v, l), v, sh_l(v, r));
      if (jj == 1) raw0 = v;
      if (jj == 2) raw1 = v;
    }
    #pragma unroll
    for (int j = 0; j < 2; ++j) {
      int gy = y0 + rsd + j;
      half8 up = (gy >= 1)    ? rmx[j]     : splat8(-BIGF);
      half8 dn = (gy <= 1022) ? rmx[j + 2] : splat8(-BIGF);
      half8 opened = vmax3(up, rmx[j + 1], dn);
      half8 d = img[j] - opened;
      d = __builtin_elementwise_max(d, splat8(0.0f));
      skel[j] = __builtin_elementwise_max(skel[j], d);
    }
    img[0] = raw0;
    img[1] = raw1;
    { _Float16* tmp = P; P = Q; Q = tmp; }
  }

  // ---- fused reduction: s0 = sum(skel*other), s1 = sum(skel) ----
  float s0 = 0.f, s1 = 0.f;
  #pragma unroll
  for (int j = 0; j < 2; ++j) {
    int gy = y0 + rsd + j;
    const size_t g = base + (size_t)gy * 1024 + gx0d;
    const float4 f0 = *(const float4*)&osrc[g];
    const float4 f1 = *(const float4*)&osrc[g + 4];
    float ff[8] = {f0.x, f0.y, f0.z, f0.w, f1.x, f1.y, f1.z, f1.w};
    #pragma unroll
    for (int e = 0; e < 8; ++e) {
      float o = (s == 1) ? sigmoidf_(ff[e]) : ff[e];
      float sk = (float)skel[j][e];
      s0 += sk * o;
      s1 += sk;
    }
  }
  for (int off = 32; off >= 1; off >>= 1) {
    s0 += __shfl_down(s0, off, 64);
    s1 += __shfl_down(s1, off, 64);
  }
  __syncthreads();  // protect last dilate's reads before reusing LA
  float* red = (float*)LA;
  const int lane = t & 63, wv = t >> 6;
  if (lane == 0) { red[wv * 2] = s0; red[wv * 2 + 1] = s1; }
  __syncthreads();
  if (t == 0) {
    atomicAdd(&sums[(s * 32 + b) * 2 + 0], red[0] + red[2] + red[4] + red[6]);
    atomicAdd(&sums[(s * 32 + b) * 2 + 1], red[1] + red[3] + red[5] + red[7]);
  }
}

__global__ void finalize_kernel(const float* __restrict__ sums,
                                float* __restrict__ out)
{
  const int t = threadIdx.x;  // 64 threads
  float cl = 0.f;
  if (t < 32) {
    float pn = sums[t * 2 + 0],        pd = sums[t * 2 + 1];
    float sn = sums[(32 + t) * 2 + 0], sd = sums[(32 + t) * 2 + 1];
    float tprec = pn / (pd + 1e-6f);
    float tsens = sn / (sd + 1e-6f);
    cl = 2.f * tprec * tsens / (tprec + tsens + 1e-6f);
  }
  for (int off = 32; off >= 1; off >>= 1) cl += __shfl_down(cl, off, 64);
  if (t == 0) out[0] = 1.f - cl / 32.f;
}

extern "C" void kernel_launch(void* const* d_in, const int* in_sizes, int n_in,
                              void* d_out, int out_size, void* d_ws, size_t ws_size,
                              hipStream_t stream) {
  const float* pred = (const float*)d_in[0];
  const float* gt   = (const float*)d_in[1];
  float* sums = (float*)d_ws;  // 128 floats: [tensor][batch][{prod,sum}]
  hipMemsetAsync(sums, 0, 128 * sizeof(float), stream);
  dim3 grid(256, 32, 2);
  skel_tile_kernel<<<grid, dim3(256), 0, stream>>>(pred, gt, sums);
  finalize_kernel<<<1, 64, 0, stream>>>(sums, (float*)d_out);
}